// Round 3
// baseline (1168.087 us; speedup 1.0000x reference)
//
#include <hip/hip_runtime.h>
#include <hip/hip_bf16.h>
#include <stdint.h>

// Problem constants
#define T_TOK 8192      // B*S tokens
#define DMODEL 1024
#define FFDIM 4096
#define NEXP 8
#define TOPK 2
#define MTILES 72               // 256-row tiles: 16384 + 8*255 <= 72*256
#define ROWS_PAD (MTILES * 256) // 18432

typedef __bf16 bf16x8 __attribute__((ext_vector_type(8)));
typedef float f32x4 __attribute__((ext_vector_type(4)));

__device__ __forceinline__ unsigned short f2bf(float f) {
    union { float f; unsigned u; } v; v.f = f;
    unsigned u = v.u;
    u += 0x7fffu + ((u >> 16) & 1u);   // round-to-nearest-even
    return (unsigned short)(u >> 16);
}

// ---------------- init: zero out region, row_token=-1, zero_row, counters ----
__global__ void init_kernel(float* __restrict__ out0, int* __restrict__ row_token,
                            unsigned short* __restrict__ zero_row, int* __restrict__ cnt_fill) {
    size_t i = (size_t)blockIdx.x * blockDim.x + threadIdx.x;
    if (i < (size_t)T_TOK * DMODEL) out0[i] = 0.f;
    if (i < ROWS_PAD) row_token[i] = -1;
    if (i < DMODEL) zero_row[i] = 0;
    if (i < 32) cnt_fill[i] = 0;   // cnt[8] + fill[8] + job queues
}

// ---------------- fp32 -> bf16 conversion (vectorized) -----------------------
__global__ void cvt_kernel(const float* __restrict__ src, unsigned short* __restrict__ dst, int n4) {
    int i = blockIdx.x * blockDim.x + threadIdx.x;
    if (i < n4) {
        float4 v = ((const float4*)src)[i];
        ushort4 o;
        o.x = f2bf(v.x); o.y = f2bf(v.y); o.z = f2bf(v.z); o.w = f2bf(v.w);
        ((ushort4*)dst)[i] = o;
    }
}

// ---------------- gating: one wave per token, fp64 accumulation --------------
__global__ __launch_bounds__(256)
void gate_kernel(const float* __restrict__ x, const float* __restrict__ wg,
                 const float* __restrict__ bg,
                 float* __restrict__ out_idx, float* __restrict__ out_val,
                 int* __restrict__ tok_e, float* __restrict__ tok_g, int* __restrict__ cnt) {
    int t = blockIdx.x * 4 + (threadIdx.x >> 6);
    int lane = threadIdx.x & 63;
    const float4* xr = (const float4*)(x + (size_t)t * DMODEL);
    double acc[NEXP];
#pragma unroll
    for (int e = 0; e < NEXP; ++e) acc[e] = 0.0;
#pragma unroll
    for (int it = 0; it < 4; ++it) {
        float4 xv = xr[lane + it * 64];
#pragma unroll
        for (int e = 0; e < NEXP; ++e) {
            float4 wv = ((const float4*)(wg + e * DMODEL))[lane + it * 64];
            acc[e] += (double)xv.x * wv.x + (double)xv.y * wv.y +
                      (double)xv.z * wv.z + (double)xv.w * wv.w;
        }
    }
#pragma unroll
    for (int off = 32; off; off >>= 1)
#pragma unroll
        for (int e = 0; e < NEXP; ++e) acc[e] += __shfl_down(acc[e], off, 64);
    if (lane == 0) {
        double lg[NEXP], mx = -1e300;
#pragma unroll
        for (int e = 0; e < NEXP; ++e) { lg[e] = acc[e] + (double)bg[e]; mx = lg[e] > mx ? lg[e] : mx; }
        double p[NEXP], s = 0.0;
#pragma unroll
        for (int e = 0; e < NEXP; ++e) { p[e] = exp(lg[e] - mx); s += p[e]; }
#pragma unroll
        for (int e = 0; e < NEXP; ++e) p[e] /= s;
        int i0 = 0;
#pragma unroll
        for (int e = 1; e < NEXP; ++e) if (p[e] > p[i0]) i0 = e;
        int i1 = (i0 == 0) ? 1 : 0;
#pragma unroll
        for (int e = 0; e < NEXP; ++e) if (e != i0 && p[e] > p[i1]) i1 = e;
        out_idx[t * 2 + 0] = (float)i0;
        out_idx[t * 2 + 1] = (float)i1;
        out_val[t * 2 + 0] = (float)p[i0];
        out_val[t * 2 + 1] = (float)p[i1];
        tok_e[t * 2 + 0] = i0; tok_e[t * 2 + 1] = i1;
        tok_g[t * 2 + 0] = (float)p[i0]; tok_g[t * 2 + 1] = (float)p[i1];
        atomicAdd(&cnt[i0], 1);
        atomicAdd(&cnt[i1], 1);
    }
}

// ---------------- 256-padded segment offsets ---------------------------------
__global__ void offsets_kernel(const int* __restrict__ cnt, int* __restrict__ off_pad) {
    if (threadIdx.x == 0 && blockIdx.x == 0) {
        int o = 0;
        off_pad[0] = 0;
#pragma unroll
        for (int e = 0; e < NEXP; ++e) {
            o += ((cnt[e] + 255) >> 8) << 8;
            off_pad[e + 1] = o;
        }
    }
}

// ---------------- scatter tokens into padded row space -----------------------
__global__ void scatter_kernel(const int* __restrict__ tok_e, const float* __restrict__ tok_g,
                               const int* __restrict__ off_pad, int* __restrict__ fill,
                               int* __restrict__ row_token, float* __restrict__ row_gate) {
    int i = blockIdx.x * blockDim.x + threadIdx.x;
    if (i < T_TOK * TOPK) {
        int e = tok_e[i];
        int pos = off_pad[e] + atomicAdd(&fill[e], 1);
        row_token[pos] = i >> 1;
        row_gate[pos] = tok_g[i];
    }
}

// ---------------- grouped GEMM: persistent blocks + dynamic job queue --------
// C = A * W^T. 256 persistent blocks (1/CU, 128 KiB LDS), 512 thr = 8 waves
// (2M x 4N), per-wave output 128x64. Jobs: x (M-tile) major, y (N-tile)
// FASTEST -> consumers of the same A panel are temporally adjacent (L2/L3 hot).
// MODE1 splits K ZD=4 ways (NT=32 per job) so both modes have 1152 equal jobs:
// makespan 5/4.5 rounds vs the old 3/2.25 for 576 blocks.
// Inner schedule (unchanged from R2 except sched_barrier removed):
//   ring of 4 x 32KB K-tiles; per tile 2 fine phases
//   {ds_read frags; stage(t+3) half; s_barrier; lgkmcnt(0); setprio(1);
//    16 MFMA; setprio(0); s_barrier}; tile end: COUNTED vmcnt(8) + barrier.
// Job boundary: __syncthreads() (full vmcnt/lgkm drain) -> epilogue stores
// retired before the next prologue's counted waits; ring safe since NT%4==0
// (last tile uses slot 3, new prologue writes slots 0..2).
// MODE 0: A = gathered x_bf16 rows, store h = leakyrelu(C + b1) as bf16
// MODE 1: A = h rows, atomicAdd gate*(C + [z==0]*b2) into out
template <int MODE, int KD, int ND, int YD, int ZD>
__global__ __launch_bounds__(512, 2)
void moe_gemm(const unsigned short* __restrict__ A, const unsigned short* __restrict__ W,
              const float* __restrict__ bias, const int* __restrict__ row_token,
              const float* __restrict__ row_gate, const int* __restrict__ off_pad,
              const unsigned short* __restrict__ zero_row,
              unsigned short* __restrict__ Hout, float* __restrict__ Out,
              int* __restrict__ jobq) {
    __shared__ __attribute__((aligned(16))) unsigned short As[4 * 256 * 32];
    __shared__ __attribute__((aligned(16))) unsigned short Bs[4 * 256 * 32];
    __shared__ int jobShared;
    constexpr int NJOBS = MTILES * YD * ZD;
    constexpr int NT = KD / ZD / 32;          // 32 for both instantiations
    static_assert(NT % 4 == 0, "ring-slot safety at job boundary needs NT%4==0");

    const int tid = threadIdx.x;
    const int wave = tid >> 6;
    const int lane = tid & 63;
    const int wm = wave >> 2, wn = wave & 3;       // 2 x 4 wave grid
    const int lane15 = lane & 15;
    const int quad = lane >> 4;

    // staging geometry: 256 rows x 4 chunks (16B) per matrix = 1024 chunks,
    // 2 rounds of 512 threads. row = rr*128 + (tid>>2), logical chunk = tid&3.
    // swizzled source chunk: (tid&3) ^ ((row>>1)&3), rr-invariant.
    const int scol = (tid & 3) ^ ((tid >> 3) & 3);

    const int rowA = wm * 128 + lane15;    // + i*16 per fragment
    const int rowB = wn * 64 + lane15;     // + j*16 per fragment
    const int pcs = ((quad ^ ((lane15 >> 1) & 3)) * 8);  // physical chunk (shorts)

    // expert boundaries are job-invariant: hoist
    int offp[NEXP - 1];
#pragma unroll
    for (int q = 0; q < NEXP - 1; ++q) offp[q] = off_pad[q + 1];

    const unsigned short* aptr[2];
    const unsigned short* bptr[2];

    auto stageA = [&](int tt) {
        const int bo = (tt & 3) * 8192;
        const int koff = tt * 32;
#pragma unroll
        for (int rr = 0; rr < 2; ++rr)
            __builtin_amdgcn_global_load_lds(
                (const __attribute__((address_space(1))) void*)(aptr[rr] + koff),
                (__attribute__((address_space(3))) void*)(As + bo + (rr * 512 + wave * 64) * 8), 16, 0, 0);
    };
    auto stageB = [&](int tt) {
        const int bo = (tt & 3) * 8192;
        const int koff = tt * 32;
#pragma unroll
        for (int rr = 0; rr < 2; ++rr)
            __builtin_amdgcn_global_load_lds(
                (const __attribute__((address_space(1))) void*)(bptr[rr] + koff),
                (__attribute__((address_space(3))) void*)(Bs + bo + (rr * 512 + wave * 64) * 8), 16, 0, 0);
    };

    while (true) {
        __syncthreads();                       // drain prior job (stores + LDS)
        if (tid == 0) jobShared = atomicAdd(jobq, 1);
        __syncthreads();                       // jobShared visible to all waves
        const int j = jobShared;
        if (j >= NJOBS) break;

        // decode: y fastest, then z, then x  -> A-panel reuse is adjacent
        const int x = j / (YD * ZD);
        const int rem = j % (YD * ZD);
        const int z = rem / YD;
        const int y = rem % YD;
        const int m0 = x * 256;
        const int n0 = y * 256;
        const int kbase = z * (KD / ZD);

        int e = 0;
#pragma unroll
        for (int q = 0; q < NEXP - 1; ++q)
            if (offp[q] <= m0) e = q + 1;

#pragma unroll
        for (int rr = 0; rr < 2; ++rr) {
            int row = rr * 128 + (tid >> 2);
            const unsigned short* ab;
            if (MODE == 0) {
                int tok = row_token[m0 + row];
                ab = (tok < 0) ? zero_row : (A + (size_t)tok * KD);
            } else {
                ab = A + (size_t)(m0 + row) * KD;
            }
            aptr[rr] = ab + kbase + scol * 8;
            bptr[rr] = W + ((size_t)e * ND + (size_t)(n0 + row)) * (size_t)KD + kbase + scol * 8;
        }

        f32x4 acc[8][4];
#pragma unroll
        for (int i = 0; i < 8; ++i)
#pragma unroll
            for (int jj = 0; jj < 4; ++jj) acc[i][jj] = (f32x4)0.f;

        // prologue: fill 3 ring slots (12 loads in flight), certify tile 0
        stageA(0); stageB(0); stageA(1); stageB(1); stageA(2); stageB(2);
        asm volatile("s_waitcnt vmcnt(8)" ::: "memory");
        __builtin_amdgcn_s_barrier();

        for (int t = 0; t < NT; ++t) {
            const int bo = (t & 3) * 8192;
            // -------- phase 0: C-rows 0..63 of this wave --------
            bf16x8 af0[4], bfv[4];
#pragma unroll
            for (int i = 0; i < 4; ++i)
                af0[i] = *(const bf16x8*)(As + bo + (rowA + i * 16) * 32 + pcs);
#pragma unroll
            for (int jj = 0; jj < 4; ++jj)
                bfv[jj] = *(const bf16x8*)(Bs + bo + (rowB + jj * 16) * 32 + pcs);
            if (t + 3 < NT) stageA(t + 3);
            __builtin_amdgcn_s_barrier();
            asm volatile("s_waitcnt lgkmcnt(0)" ::: "memory");
            __builtin_amdgcn_s_setprio(1);
#pragma unroll
            for (int i = 0; i < 4; ++i)
#pragma unroll
                for (int jj = 0; jj < 4; ++jj)
                    acc[i][jj] = __builtin_amdgcn_mfma_f32_16x16x32_bf16(af0[i], bfv[jj], acc[i][jj], 0, 0, 0);
            __builtin_amdgcn_s_setprio(0);
            __builtin_amdgcn_s_barrier();
            // -------- phase 1: C-rows 64..127 (bfv reused from registers) ----
            bf16x8 af1[4];
#pragma unroll
            for (int i = 0; i < 4; ++i)
                af1[i] = *(const bf16x8*)(As + bo + (rowA + 64 + i * 16) * 32 + pcs);
            if (t + 3 < NT) stageB(t + 3);
            __builtin_amdgcn_s_barrier();
            asm volatile("s_waitcnt lgkmcnt(0)" ::: "memory");
            __builtin_amdgcn_s_setprio(1);
#pragma unroll
            for (int i = 0; i < 4; ++i)
#pragma unroll
                for (int jj = 0; jj < 4; ++jj)
                    acc[4 + i][jj] = __builtin_amdgcn_mfma_f32_16x16x32_bf16(af1[i], bfv[jj], acc[4 + i][jj], 0, 0, 0);
            __builtin_amdgcn_s_setprio(0);
            // -------- tile end: certify tile t+1 with counted vmcnt --------
            if (t < NT - 1) {
                if (t < NT - 3)       asm volatile("s_waitcnt vmcnt(8)" ::: "memory");
                else if (t == NT - 3) asm volatile("s_waitcnt vmcnt(4)" ::: "memory");
                else                  asm volatile("s_waitcnt vmcnt(0)" ::: "memory");
                __builtin_amdgcn_s_barrier();
            }
        }

        // epilogue (stores not drained here; next job's __syncthreads does it)
        const bool add_bias = (MODE == 0) || (kbase == 0);
        float bv[4];
#pragma unroll
        for (int jj = 0; jj < 4; ++jj)
            bv[jj] = bias[e * ND + n0 + wn * 64 + jj * 16 + lane15];
#pragma unroll
        for (int i = 0; i < 8; ++i) {
#pragma unroll
            for (int r4 = 0; r4 < 4; ++r4) {
                int m = m0 + wm * 128 + i * 16 + quad * 4 + r4;
                int tok = 0; float g = 0.f;
                if (MODE == 1) { tok = row_token[m]; g = row_gate[m]; }
#pragma unroll
                for (int jj = 0; jj < 4; ++jj) {
                    int n = n0 + wn * 64 + jj * 16 + lane15;
                    float v = acc[i][jj][r4] + (add_bias ? bv[jj] : 0.f);
                    if (MODE == 0) {
                        v = v > 0.f ? v : 0.1f * v;
                        Hout[(size_t)m * ND + n] = f2bf(v);
                    } else {
                        if (tok >= 0) atomicAdd(Out + (size_t)tok * ND + n, g * v);
                    }
                }
            }
        }
    }
}

extern "C" void kernel_launch(void* const* d_in, const int* in_sizes, int n_in,
                              void* d_out, int out_size, void* d_ws, size_t ws_size,
                              hipStream_t stream) {
    const float* x  = (const float*)d_in[0];
    const float* wg = (const float*)d_in[1];
    const float* bg = (const float*)d_in[2];
    const float* w1 = (const float*)d_in[3];
    const float* b1 = (const float*)d_in[4];
    const float* w2 = (const float*)d_in[5];
    const float* b2 = (const float*)d_in[6];
    float* out0 = (float*)d_out;
    float* out_idx = out0 + (size_t)T_TOK * DMODEL;
    float* out_val = out_idx + T_TOK * TOPK;

    char* p = (char*)d_ws;
    auto alloc = [&](size_t bytes) {
        char* q = p;
        p += (bytes + 255) & ~(size_t)255;
        return q;
    };
    unsigned short* xb  = (unsigned short*)alloc((size_t)T_TOK * DMODEL * 2);
    unsigned short* w1b = (unsigned short*)alloc((size_t)NEXP * FFDIM * DMODEL * 2);
    unsigned short* w2b = (unsigned short*)alloc((size_t)NEXP * DMODEL * FFDIM * 2);
    unsigned short* hb  = (unsigned short*)alloc((size_t)ROWS_PAD * FFDIM * 2);
    unsigned short* zrow = (unsigned short*)alloc(DMODEL * 2);
    int* cnt = (int*)alloc(128);  // cnt[8] + fill[8] + jobq[2]
    int* fill = cnt + 8;
    int* jobq0 = cnt + 16;
    int* jobq1 = cnt + 17;
    int* off_pad = (int*)alloc(64);
    int* tok_e = (int*)alloc((size_t)T_TOK * TOPK * 4);
    float* tok_g = (float*)alloc((size_t)T_TOK * TOPK * 4);
    int* row_token = (int*)alloc((size_t)ROWS_PAD * 4);
    float* row_gate = (float*)alloc((size_t)ROWS_PAD * 4);
    if ((size_t)(p - (char*)d_ws) > ws_size) return;  // ws too small: fail visibly, no OOB

    init_kernel<<<(T_TOK * DMODEL + 255) / 256, 256, 0, stream>>>(out0, row_token, zrow, cnt);
    cvt_kernel<<<(T_TOK * DMODEL / 4 + 255) / 256, 256, 0, stream>>>(x, xb, T_TOK * DMODEL / 4);
    cvt_kernel<<<(NEXP * FFDIM * DMODEL / 4 + 255) / 256, 256, 0, stream>>>(w1, w1b, NEXP * FFDIM * DMODEL / 4);
    cvt_kernel<<<(NEXP * DMODEL * FFDIM / 4 + 255) / 256, 256, 0, stream>>>(w2, w2b, NEXP * DMODEL * FFDIM / 4);
    gate_kernel<<<T_TOK / 4, 256, 0, stream>>>(x, wg, bg, out_idx, out_val, tok_e, tok_g, cnt);
    offsets_kernel<<<1, 64, 0, stream>>>(cnt, off_pad);
    scatter_kernel<<<(T_TOK * TOPK + 255) / 256, 256, 0, stream>>>(tok_e, tok_g, off_pad, fill, row_token, row_gate);
    // MODE0: 72 x-tiles x 16 y-tiles (y fastest), full K=1024
    moe_gemm<0, DMODEL, FFDIM, 16, 1><<<256, 512, 0, stream>>>(
        xb, w1b, b1, row_token, row_gate, off_pad, zrow, hb, nullptr, jobq0);
    // MODE1: 72 x-tiles x 4 y-tiles x 4 K-splits (y fastest), K-slice=1024
    moe_gemm<1, FFDIM, DMODEL, 4, 4><<<256, 512, 0, stream>>>(
        hb, w2b, b2, row_token, row_gate, off_pad, zrow, nullptr, out0, jobq1);
}